// Round 1
// baseline (735.701 us; speedup 1.0000x reference)
//
#include <hip/hip_runtime.h>
#include <stdint.h>

// Shapes assumed (fixed by the problem): D=300 (KP1=320), H=600 (KP2=608), D%4==0.

// ---------- helpers ----------
typedef __attribute__((ext_vector_type(8))) short short8;
typedef __attribute__((ext_vector_type(4))) short short4v;
typedef __attribute__((ext_vector_type(4))) float float4v;

__device__ inline float b2f(unsigned short u) {
  union { unsigned int i; float f; } v; v.i = ((unsigned int)u) << 16; return v.f;
}
__device__ inline unsigned short f2b(float f) {
  union { float f; unsigned int i; } v; v.f = f;
  unsigned int i = v.i;
  i += 0x7fffu + ((i >> 16) & 1u);   // round-to-nearest-even
  return (unsigned short)(i >> 16);
}

// ---------- transpose fp32 -> bf16, zero-padded output (pad pre-zeroed by memset) ----------
__global__ void transpose_pad(const float* __restrict__ in, short* __restrict__ out,
                              int R, int C, int outStride, int total) {
  int idx = blockIdx.x * blockDim.x + threadIdx.x;
  if (idx >= total) return;
  int r = idx / C, c = idx - r * C;
  out[(size_t)c * outStride + r] = (short)f2b(in[idx]);
}

// ---------- combined edge-embedding table: w01[f0*NUM1+f1][d] = w0[f0][d]+w1[f1][d] ----------
__global__ void build_w01(const float* __restrict__ w0, const float* __restrict__ w1,
                          float* __restrict__ w01, int D, int NUM1, int total) {
  int i = blockIdx.x * blockDim.x + threadIdx.x;
  if (i >= total) return;
  int f01 = i / D, d = i - f01 * D;
  int f0 = f01 / NUM1, f1 = f01 - f0 * NUM1;
  w01[i] = w0[f0 * D + d] + w1[f1 * D + d];
}

// ---------- CSR build: count, scan, fill ----------
__global__ void count_deg(const int* __restrict__ dst, int* __restrict__ deg, int E) {
  int e = blockIdx.x * blockDim.x + threadIdx.x;
  if (e < E) atomicAdd(&deg[dst[e]], 1);
}

__global__ void scan1(const int* __restrict__ deg, int* __restrict__ offp,
                      int* __restrict__ bsum, int n) {
  __shared__ int sh[256];
  const int t = threadIdx.x;
  const int base = blockIdx.x * 1024 + t * 4;
  int v[4], s = 0;
#pragma unroll
  for (int j = 0; j < 4; ++j) { int i = base + j; v[j] = (i < n) ? deg[i] : 0; s += v[j]; }
  sh[t] = s;
  __syncthreads();
  for (int d = 1; d < 256; d <<= 1) {
    int x = (t >= d) ? sh[t - d] : 0;
    __syncthreads();
    sh[t] += x;
    __syncthreads();
  }
  int excl = (t > 0) ? sh[t - 1] : 0;
  if (t == 255) bsum[blockIdx.x] = sh[255];
#pragma unroll
  for (int j = 0; j < 4; ++j) { int i = base + j; if (i < n) offp[i] = excl; excl += v[j]; }
}

__global__ void scan2(int* __restrict__ bsum, int nb) {
  __shared__ int sh[256];
  const int t = threadIdx.x;
  sh[t] = (t < nb) ? bsum[t] : 0;
  __syncthreads();
  for (int d = 1; d < 256; d <<= 1) {
    int x = (t >= d) ? sh[t - d] : 0;
    __syncthreads();
    sh[t] += x;
    __syncthreads();
  }
  if (t < nb) bsum[t] = (t > 0) ? sh[t - 1] : 0;
}

// fill CSR with pre-gathered per-edge payload: {src, f0*NUM1+f1}
__global__ void fill_csr(const int* __restrict__ dst, const int* __restrict__ src,
                         const int* __restrict__ ef0, const int* __restrict__ ef1,
                         const int* __restrict__ offp, const int* __restrict__ bsum,
                         int* __restrict__ tmp, int2* __restrict__ ebp, int NUM1, int E) {
  int e = blockIdx.x * blockDim.x + threadIdx.x;
  if (e >= E) return;
  int dn = dst[e];
  int pos = offp[dn] + bsum[dn >> 10] + atomicAdd(&tmp[dn], 1);
  ebp[pos] = make_int2(src[e], ef0[e] * NUM1 + ef1[e]);
}

// ---------- gather: aggb[node] = sum_e (nf[src]+w01[f01]) + deg*(b0+b1), bf16 out ----------
__global__ void gather_agg(const float* __restrict__ nf, const float* __restrict__ w01,
                           const float* __restrict__ b0f, const float* __restrict__ b1f,
                           const int* __restrict__ deg, const int* __restrict__ offp,
                           const int* __restrict__ bsum, const int2* __restrict__ ebp,
                           unsigned short* __restrict__ aggb,
                           int D, int ldab, int total) {
  int idx = blockIdx.x * blockDim.x + threadIdx.x;
  if (idx >= total) return;
  const int quads = ldab >> 2;
  int node = idx / quads;
  int q = idx - node * quads;
  int d = q * 4;
  unsigned short* op = &aggb[(size_t)node * ldab + d];
  if (d >= D) {  // zero the pad columns so GEMM1's A pad is clean
    short4v z = {0, 0, 0, 0};
    *(short4v*)op = z;
    return;
  }
  int dg = deg[node];
  int o = offp[node] + bsum[node >> 10];
  float4v acc = {0.f, 0.f, 0.f, 0.f};
  for (int j = 0; j < dg; ++j) {
    int2 p = ebp[o + j];
    float4v nv = *(const float4v*)&nf[(size_t)p.x * D + d];
    float4v wv = *(const float4v*)&w01[(size_t)p.y * D + d];
    acc += nv + wv;
  }
  float4v bb = *(const float4v*)&b0f[d];
  float4v b2v = *(const float4v*)&b1f[d];
  acc += (float)dg * (bb + b2v);
  short4v r;
#pragma unroll
  for (int j = 0; j < 4; ++j) r[j] = (short)f2b(acc[j]);
  *(short4v*)op = r;
}

// ---------- GEMM1: A-resident-in-registers MFMA GEMM ----------
// Each wave owns 64 rows; A fragments for the FULL K stay in VGPRs (KS*4 short8 = 16*KS regs).
// Loops over all N-chunks (32 cols each); B read direct from global (L2-resident, 400KB).
// No LDS, no barriers. A fetched from HBM exactly once.
// C = relu(A@B + bias), bf16, ldc cols stored (cols >= Nn get exact zeros -> clean K-pad for GEMM2).
template<int KS>
__global__ __launch_bounds__(128, 2)
void gemm_rk(const short* __restrict__ A, int lda,
             const short* __restrict__ BT, int ldbt,
             const float* __restrict__ bias,
             unsigned short* __restrict__ C, int ldc,
             int M, int Nn, int nchunks) {
  const int t = threadIdx.x;
  const int wave = t >> 6, lane = t & 63, quad = lane >> 4, lr = lane & 15;
  const int m0 = (blockIdx.x * 2 + wave) * 64;

  short8 af[KS][4];
#pragma unroll
  for (int mi = 0; mi < 4; ++mi) {
    int gm = m0 + mi * 16 + lr;
    int gmc = gm < M ? gm : (M - 1);   // clamp: rows >= M produce dead output rows only
    const short8* ap = (const short8*)(A + (size_t)gmc * lda + quad * 8);
#pragma unroll
    for (int ks = 0; ks < KS; ++ks) af[ks][mi] = ap[ks * 4];
  }

  const float4v fz = {0.f, 0.f, 0.f, 0.f};
  for (int nc = 0; nc < nchunks; ++nc) {
    const short* bp0 = BT + (size_t)(nc * 32 + lr) * ldbt + quad * 8;
    const short* bp1 = bp0 + 16 * ldbt;
    float4v acc[4][2];
#pragma unroll
    for (int mi = 0; mi < 4; ++mi) { acc[mi][0] = fz; acc[mi][1] = fz; }
#pragma unroll
    for (int ks = 0; ks < KS; ++ks) {
      short8 b0 = *(const short8*)(bp0 + ks * 32);
      short8 b1 = *(const short8*)(bp1 + ks * 32);
#pragma unroll
      for (int mi = 0; mi < 4; ++mi) {
        acc[mi][0] = __builtin_amdgcn_mfma_f32_16x16x32_bf16(af[ks][mi], b0, acc[mi][0], 0, 0, 0);
        acc[mi][1] = __builtin_amdgcn_mfma_f32_16x16x32_bf16(af[ks][mi], b1, acc[mi][1], 0, 0, 0);
      }
    }
    // epilogue: bias + relu, bf16 store. Cols in [Nn, nchunks*32) have zero B rows -> store 0.
#pragma unroll
    for (int ni = 0; ni < 2; ++ni) {
      int gn = nc * 32 + ni * 16 + lr;
      float bv = (gn < Nn) ? bias[gn] : 0.f;
#pragma unroll
      for (int mi = 0; mi < 4; ++mi) {
        int gmb = m0 + mi * 16 + quad * 4;
#pragma unroll
        for (int r = 0; r < 4; ++r) {
          int gm = gmb + r;
          float v = fmaxf(acc[mi][ni][r] + bv, 0.f);
          if (gm < M) C[(size_t)gm * ldc + gn] = f2b(v);
        }
      }
    }
  }
}

// ---------- GEMM2: stream-A, accumulators resident for 160 output cols ----------
// Wave owns 64 rows x 160 cols (acc[4][10] = 160 VGPRs). A streamed once per pass;
// grid.x = column passes (fastest-varying -> passes of same rows co-scheduled, share A in L2).
// fp32 out + column sum/sumsq stats.
__global__ __launch_bounds__(256, 2)
void gemm_sk(const short* __restrict__ A, int lda,
             const short* __restrict__ BT, int ldbt,
             const float* __restrict__ bias,
             float* __restrict__ C, int ldc,
             int M, int Nn, int KS,
             float* __restrict__ colsum, float* __restrict__ colsumsq) {
  const int t = threadIdx.x;
  const int wave = t >> 6, lane = t & 63, quad = lane >> 4, lr = lane & 15;
  const int m0 = (blockIdx.y * 4 + wave) * 64;
  const int n00 = blockIdx.x * 160;

  const float4v fz = {0.f, 0.f, 0.f, 0.f};
  float4v acc[4][10];
#pragma unroll
  for (int mi = 0; mi < 4; ++mi)
#pragma unroll
    for (int nt = 0; nt < 10; ++nt) acc[mi][nt] = fz;

  const short8* ap[4];
#pragma unroll
  for (int mi = 0; mi < 4; ++mi) {
    int gm = m0 + mi * 16 + lr;
    int gmc = gm < M ? gm : (M - 1);   // clamp; dead rows never stored / counted
    ap[mi] = (const short8*)(A + (size_t)gmc * lda + quad * 8);
  }
  const short8* bp = (const short8*)(BT + (size_t)(n00 + lr) * ldbt + quad * 8);
  const int bstride = ldbt * 2;        // short8 units per 16 B-rows

  // manual 1-deep A prefetch: next kstep's A loads issue before this kstep's MFMAs
  short8 a0 = ap[0][0], a1 = ap[1][0], a2 = ap[2][0], a3 = ap[3][0];
  for (int ks = 0; ks < KS; ++ks) {
    int kn = (ks + 1 < KS) ? (ks + 1) : ks;
    short8 n0_ = ap[0][kn * 4], n1_ = ap[1][kn * 4], n2_ = ap[2][kn * 4], n3_ = ap[3][kn * 4];
#pragma unroll
    for (int nt = 0; nt < 10; ++nt) {
      short8 bf = bp[ks * 4 + nt * bstride];
      acc[0][nt] = __builtin_amdgcn_mfma_f32_16x16x32_bf16(a0, bf, acc[0][nt], 0, 0, 0);
      acc[1][nt] = __builtin_amdgcn_mfma_f32_16x16x32_bf16(a1, bf, acc[1][nt], 0, 0, 0);
      acc[2][nt] = __builtin_amdgcn_mfma_f32_16x16x32_bf16(a2, bf, acc[2][nt], 0, 0, 0);
      acc[3][nt] = __builtin_amdgcn_mfma_f32_16x16x32_bf16(a3, bf, acc[3][nt], 0, 0, 0);
    }
    a0 = n0_; a1 = n1_; a2 = n2_; a3 = n3_;
  }

  // epilogue: bias, fp32 store, column stats
#pragma unroll
  for (int nt = 0; nt < 10; ++nt) {
    int gn = n00 + nt * 16 + lr;
    bool ncol = (gn < Nn);
    float bv = ncol ? bias[gn] : 0.f;
    float s = 0.f, q = 0.f;
#pragma unroll
    for (int mi = 0; mi < 4; ++mi) {
      int gmb = m0 + mi * 16 + quad * 4;
#pragma unroll
      for (int r = 0; r < 4; ++r) {
        int gm = gmb + r;
        float v = acc[mi][nt][r] + bv;
        if (gm < M && ncol) {
          C[(size_t)gm * ldc + gn] = v;
          s += v; q += v * v;
        }
      }
    }
    s += __shfl_xor(s, 16); q += __shfl_xor(q, 16);
    s += __shfl_xor(s, 32); q += __shfl_xor(q, 32);
    if (quad == 0 && ncol) {
      unsafeAtomicAdd(&colsum[gn], s);
      unsafeAtomicAdd(&colsumsq[gn], q);
    }
  }
}

// ---------- BatchNorm finalize: scale/shift per column ----------
__global__ void bn_finalize(const float* __restrict__ colsum, const float* __restrict__ colsumsq,
                            const float* __restrict__ gamma, const float* __restrict__ beta,
                            float2* __restrict__ ss, int D, float invN) {
  int d = blockIdx.x * blockDim.x + threadIdx.x;
  if (d >= D) return;
  float mean = colsum[d] * invN;
  float var = fmaxf(colsumsq[d] * invN - mean * mean, 0.f);
  float sc = rsqrtf(var + 1e-5f) * gamma[d];
  float sh = beta[d] - mean * sc;
  ss[d] = make_float2(sc, sh);
}

// ---------- BatchNorm apply (in place, float4 vectorized; requires D%4==0) ----------
__global__ void bn_apply4(float4v* __restrict__ out, const float2* __restrict__ ss,
                          int total4, int cquads) {
  int idx = blockIdx.x * blockDim.x + threadIdx.x;
  if (idx >= total4) return;
  int c = (idx % cquads) * 4;
  float4v v = out[idx];
  float2 p0 = ss[c], p1 = ss[c + 1], p2 = ss[c + 2], p3 = ss[c + 3];
  v[0] = v[0] * p0.x + p0.y;
  v[1] = v[1] * p1.x + p1.y;
  v[2] = v[2] * p2.x + p2.y;
  v[3] = v[3] * p3.x + p3.y;
  out[idx] = v;
}

__global__ void bn_apply1(float* __restrict__ out, const float2* __restrict__ ss,
                          int total, int D) {
  int idx = blockIdx.x * blockDim.x + threadIdx.x;
  if (idx >= total) return;
  float2 p = ss[idx % D];
  out[idx] = out[idx] * p.x + p.y;
}

// ---------- launch ----------
extern "C" void kernel_launch(void* const* d_in, const int* in_sizes, int n_in,
                              void* d_out, int out_size, void* d_ws, size_t ws_size,
                              hipStream_t stream) {
  const float* nf  = (const float*)d_in[0];
  const int*   src = (const int*)d_in[1];
  const int*   dst = (const int*)d_in[2];
  const int*   ef0 = (const int*)d_in[3];
  const int*   ef1 = (const int*)d_in[4];
  const float* ew0 = (const float*)d_in[5];
  const float* eb0 = (const float*)d_in[6];
  const float* ew1 = (const float*)d_in[7];
  const float* eb1 = (const float*)d_in[8];
  const float* w1  = (const float*)d_in[9];
  const float* b1  = (const float*)d_in[10];
  const float* w2  = (const float*)d_in[11];
  const float* b2  = (const float*)d_in[12];
  const float* gam = (const float*)d_in[13];
  const float* bet = (const float*)d_in[14];

  const int D = in_sizes[13];          // 300
  const int N = in_sizes[0] / D;       // 100000
  const int E = in_sizes[1];           // 200000
  const int H = in_sizes[10];          // 600
  const int NUM0 = in_sizes[5] / D;    // 6
  const int NUM1 = in_sizes[7] / D;    // 3
  const int KP1 = (D + 31) / 32 * 32;  // 320
  const int NP1 = (H + 63) / 64 * 64;  // 640
  const int KP2 = (H + 31) / 32 * 32;  // 608
  const int NP2 = (D + 63) / 64 * 64;  // 320
  const int nb  = (N + 1023) / 1024;   // scan blocks (<=256)

  char* ws = (char*)d_ws;
  size_t off = 0;
  // ---- zeroed region ----
  float* colsum   = (float*)(ws + off); off += 4096;
  float* colsumsq = (float*)(ws + off); off += 4096;
  short* wT1      = (short*)(ws + off); off += (size_t)NP1 * KP1 * 2;
  short* wT2      = (short*)(ws + off); off += (size_t)NP2 * KP2 * 2;
  int*   deg      = (int*)(ws + off);   off += (size_t)N * 4;
  int*   tmp      = (int*)(ws + off);   off += (size_t)N * 4;
  size_t zero_bytes = off;
  // ---- uninitialized region ----
  float2* ss      = (float2*)(ws + off); off += 4096;
  float* w01      = (float*)(ws + off);  off += (size_t)NUM0 * NUM1 * D * 4;
  int*   offp     = (int*)(ws + off);    off += (size_t)N * 4;
  int*   bsum     = (int*)(ws + off);    off += 4096;
  int2*  ebp      = (int2*)(ws + off);   off += (size_t)E * 8;
  unsigned short* aggb = (unsigned short*)(ws + off); off += (size_t)N * KP1 * 2;
  short* h1       = (short*)(ws + off);  off += (size_t)N * KP2 * 2;

  hipMemsetAsync(d_ws, 0, zero_bytes, stream);

  {  // w1: (D x H) fp32 -> wT1: (H rows x KP1 cols) bf16
    int tot = D * H;
    transpose_pad<<<(tot + 255) / 256, 256, 0, stream>>>(w1, wT1, D, H, KP1, tot);
  }
  {  // w2: (H x D) fp32 -> wT2: (D rows x KP2 cols) bf16
    int tot = H * D;
    transpose_pad<<<(tot + 255) / 256, 256, 0, stream>>>(w2, wT2, H, D, KP2, tot);
  }
  {  // combined edge-embedding table
    int tot = NUM0 * NUM1 * D;
    build_w01<<<(tot + 255) / 256, 256, 0, stream>>>(ew0, ew1, w01, D, NUM1, tot);
  }
  // ---- CSR build ----
  count_deg<<<(E + 255) / 256, 256, 0, stream>>>(dst, deg, E);
  scan1<<<nb, 256, 0, stream>>>(deg, offp, bsum, N);
  scan2<<<1, 256, 0, stream>>>(bsum, nb);
  fill_csr<<<(E + 255) / 256, 256, 0, stream>>>(dst, src, ef0, ef1, offp, bsum, tmp,
                                                ebp, NUM1, E);
  // ---- gather (atomic-free aggregation, bf16 out) ----
  {
    int total = N * (KP1 / 4);
    gather_agg<<<(total + 255) / 256, 256, 0, stream>>>(
        nf, w01, eb0, eb1, deg, offp, bsum, ebp, aggb, D, KP1, total);
  }
  {  // h1 = relu(aggb @ w1 + b1), bf16, stride KP2; stores true zeros in cols [H, KP2)
    int nblk = (N + 127) / 128;
    gemm_rk<10><<<nblk, 128, 0, stream>>>(
        (const short*)aggb, KP1, wT1, KP1, b1, (unsigned short*)h1, KP2, N, H, KP2 / 32);
  }
  {  // h = h1 @ w2 + b2 (+ column stats), fp32 out
    dim3 grid((NP2 + 159) / 160, (N + 255) / 256);
    gemm_sk<<<grid, 256, 0, stream>>>(
        h1, KP2, wT2, KP2, b2, (float*)d_out, D, N, D, KP2 / 32, colsum, colsumsq);
  }
  bn_finalize<<<(D + 255) / 256, 256, 0, stream>>>(colsum, colsumsq, gam, bet, ss, D,
                                                   1.0f / (float)N);
  if ((D & 3) == 0) {
    int total4 = N * (D / 4);
    bn_apply4<<<(total4 + 255) / 256, 256, 0, stream>>>((float4v*)d_out, ss, total4, D / 4);
  } else {
    int tot = N * D;
    bn_apply1<<<(tot + 255) / 256, 256, 0, stream>>>((float*)d_out, ss, tot, D);
  }
}

// Round 2
// 697.938 us; speedup vs baseline: 1.0541x; 1.0541x over previous
//
#include <hip/hip_runtime.h>
#include <stdint.h>

// Shapes assumed (fixed by the problem): D=300 (KP1=320), H=600 (KP2=608), D%4==0.

// ---------- helpers ----------
typedef __attribute__((ext_vector_type(8))) short short8;
typedef __attribute__((ext_vector_type(4))) short short4v;
typedef __attribute__((ext_vector_type(4))) float float4v;

__device__ inline float b2f(unsigned short u) {
  union { unsigned int i; float f; } v; v.i = ((unsigned int)u) << 16; return v.f;
}
__device__ inline unsigned short f2b(float f) {
  union { float f; unsigned int i; } v; v.f = f;
  unsigned int i = v.i;
  i += 0x7fffu + ((i >> 16) & 1u);   // round-to-nearest-even
  return (unsigned short)(i >> 16);
}

// ---------- transpose fp32 -> bf16, zero-padded output (pad pre-zeroed by memset) ----------
__global__ void transpose_pad(const float* __restrict__ in, short* __restrict__ out,
                              int R, int C, int outStride, int total) {
  int idx = blockIdx.x * blockDim.x + threadIdx.x;
  if (idx >= total) return;
  int r = idx / C, c = idx - r * C;
  out[(size_t)c * outStride + r] = (short)f2b(in[idx]);
}

// ---------- combined edge-embedding table: w01[f0*NUM1+f1][d] = w0[f0][d]+w1[f1][d] ----------
__global__ void build_w01(const float* __restrict__ w0, const float* __restrict__ w1,
                          float* __restrict__ w01, int D, int NUM1, int total) {
  int i = blockIdx.x * blockDim.x + threadIdx.x;
  if (i >= total) return;
  int f01 = i / D, d = i - f01 * D;
  int f0 = f01 / NUM1, f1 = f01 - f0 * NUM1;
  w01[i] = w0[f0 * D + d] + w1[f1 * D + d];
}

// ---------- CSR build: count, scan, fill ----------
__global__ void count_deg(const int* __restrict__ dst, int* __restrict__ deg, int E) {
  int e = blockIdx.x * blockDim.x + threadIdx.x;
  if (e < E) atomicAdd(&deg[dst[e]], 1);
}

__global__ void scan1(const int* __restrict__ deg, int* __restrict__ offp,
                      int* __restrict__ bsum, int n) {
  __shared__ int sh[256];
  const int t = threadIdx.x;
  const int base = blockIdx.x * 1024 + t * 4;
  int v[4], s = 0;
#pragma unroll
  for (int j = 0; j < 4; ++j) { int i = base + j; v[j] = (i < n) ? deg[i] : 0; s += v[j]; }
  sh[t] = s;
  __syncthreads();
  for (int d = 1; d < 256; d <<= 1) {
    int x = (t >= d) ? sh[t - d] : 0;
    __syncthreads();
    sh[t] += x;
    __syncthreads();
  }
  int excl = (t > 0) ? sh[t - 1] : 0;
  if (t == 255) bsum[blockIdx.x] = sh[255];
#pragma unroll
  for (int j = 0; j < 4; ++j) { int i = base + j; if (i < n) offp[i] = excl; excl += v[j]; }
}

__global__ void scan2(int* __restrict__ bsum, int nb) {
  __shared__ int sh[256];
  const int t = threadIdx.x;
  sh[t] = (t < nb) ? bsum[t] : 0;
  __syncthreads();
  for (int d = 1; d < 256; d <<= 1) {
    int x = (t >= d) ? sh[t - d] : 0;
    __syncthreads();
    sh[t] += x;
    __syncthreads();
  }
  if (t < nb) bsum[t] = (t > 0) ? sh[t - 1] : 0;
}

// fill CSR with pre-gathered per-edge payload: {src, f0*NUM1+f1}
__global__ void fill_csr(const int* __restrict__ dst, const int* __restrict__ src,
                         const int* __restrict__ ef0, const int* __restrict__ ef1,
                         const int* __restrict__ offp, const int* __restrict__ bsum,
                         int* __restrict__ tmp, int2* __restrict__ ebp, int NUM1, int E) {
  int e = blockIdx.x * blockDim.x + threadIdx.x;
  if (e >= E) return;
  int dn = dst[e];
  int pos = offp[dn] + bsum[dn >> 10] + atomicAdd(&tmp[dn], 1);
  ebp[pos] = make_int2(src[e], ef0[e] * NUM1 + ef1[e]);
}

// ---------- gather: aggb[node] = sum_e (nf[src]+w01[f01]) + deg*(b0+b1), bf16 out ----------
__global__ void gather_agg(const float* __restrict__ nf, const float* __restrict__ w01,
                           const float* __restrict__ b0f, const float* __restrict__ b1f,
                           const int* __restrict__ deg, const int* __restrict__ offp,
                           const int* __restrict__ bsum, const int2* __restrict__ ebp,
                           unsigned short* __restrict__ aggb,
                           int D, int ldab, int total) {
  int idx = blockIdx.x * blockDim.x + threadIdx.x;
  if (idx >= total) return;
  const int quads = ldab >> 2;
  int node = idx / quads;
  int q = idx - node * quads;
  int d = q * 4;
  unsigned short* op = &aggb[(size_t)node * ldab + d];
  if (d >= D) {  // zero the pad columns so GEMM1's A pad is clean
    short4v z = {0, 0, 0, 0};
    *(short4v*)op = z;
    return;
  }
  int dg = deg[node];
  int o = offp[node] + bsum[node >> 10];
  float4v acc = {0.f, 0.f, 0.f, 0.f};
  for (int j = 0; j < dg; ++j) {
    int2 p = ebp[o + j];
    float4v nv = *(const float4v*)&nf[(size_t)p.x * D + d];
    float4v wv = *(const float4v*)&w01[(size_t)p.y * D + d];
    acc += nv + wv;
  }
  float4v bb = *(const float4v*)&b0f[d];
  float4v b2v = *(const float4v*)&b1f[d];
  acc += (float)dg * (bb + b2v);
  short4v r;
#pragma unroll
  for (int j = 0; j < 4; ++j) r[j] = (short)f2b(acc[j]);
  *(short4v*)op = r;
}

// ---------- MFMA GEMM: C = act(A @ B + bias), LDS-staged, XCD-swizzled ----------
// A bf16 (lda 16B-aligned rows, zero-padded K), BT: [n][k] bf16 ldbt (zero-padded).
// 1-D grid, linearized w = by*ncolb + bx (column fastest). Bijective chunk swizzle maps
// consecutive w to the SAME XCD so all column-blocks of a row panel share A through that
// XCD's L2 (HBM fetches A once instead of ncolb times).
// Stores cols [0, storeN): value for gn < Nn, exact zero for [Nn, storeN) (clean K-pad).
template<bool RELU, bool STATS, bool CF32>
__global__ __launch_bounds__(256)
void gemm_bias(const short* __restrict__ A, int lda,
               const short* __restrict__ BT, int ldbt, int Brows,
               const float* __restrict__ bias,
               void* __restrict__ Cv, int ldc, int storeN,
               int M, int Nn, int KP, int ncolb,
               float* __restrict__ colsum, float* __restrict__ colsumsq) {
  constexpr int BM = 128, BN = 128, BK = 32, SA = 40;  // SA: padded LDS stride (bf16)
  __shared__ __align__(16) short Al[BM * SA];
  __shared__ __align__(16) short Bl[BN * SA];

  // ---- bijective XCD chunk swizzle (dispatch round-robins blockIdx.x % 8 over XCDs) ----
  const int nwg = gridDim.x;
  const int b = blockIdx.x;
  const int qq = nwg >> 3, rr = nwg & 7;
  const int xcd = b & 7, ii = b >> 3;
  const int w = ((xcd < rr) ? xcd * (qq + 1) : rr * (qq + 1) + (xcd - rr) * qq) + ii;
  const int by = w / ncolb, bx = w - by * ncolb;
  const int m0 = by * BM;
  const int n0 = bx * BN;

  const int t = threadIdx.x;
  const int wave = t >> 6, lane = t & 63, quad = lane >> 4, lr = lane & 15;
  const int wm = (wave >> 1) * 64, wn = (wave & 1) * 64;

  const float4v fzero = {0.f, 0.f, 0.f, 0.f};
  float4v acc[4][4];
#pragma unroll
  for (int mi = 0; mi < 4; ++mi)
#pragma unroll
    for (int ni = 0; ni < 4; ++ni) acc[mi][ni] = fzero;

  const short8 z8 = {0, 0, 0, 0, 0, 0, 0, 0};

  for (int k0 = 0; k0 < KP; k0 += BK) {
    __syncthreads();
    // ---- stage A tile (BM x BK) ----
#pragma unroll
    for (int l = 0; l < 2; ++l) {
      int g = t + l * 256;            // 0..511
      int row = g >> 2, c = (g & 3) << 3;
      int gm = m0 + row;
      short8 v = z8;
      if (gm < M)
        v = *(const short8*)&A[(size_t)gm * lda + k0 + c];
      *(short8*)&Al[row * SA + c] = v;
    }
    // ---- stage BT tile (BN x BK); guard rows beyond Brows ----
#pragma unroll
    for (int l = 0; l < 2; ++l) {
      int g = t + l * 256;
      int row = g >> 2, c = (g & 3) << 3;
      int gb = n0 + row;
      short8 v = z8;
      if (gb < Brows)
        v = *(const short8*)&BT[(size_t)gb * ldbt + k0 + c];
      *(short8*)&Bl[row * SA + c] = v;
    }
    __syncthreads();
    // ---- fragments + MFMA (wave tile 64x64, 16 MFMA per k-step) ----
    short8 af[4], bfr[4];
#pragma unroll
    for (int mi = 0; mi < 4; ++mi)
      af[mi] = *(short8*)&Al[(wm + mi * 16 + lr) * SA + quad * 8];
#pragma unroll
    for (int ni = 0; ni < 4; ++ni)
      bfr[ni] = *(short8*)&Bl[(wn + ni * 16 + lr) * SA + quad * 8];
#pragma unroll
    for (int mi = 0; mi < 4; ++mi)
#pragma unroll
      for (int ni = 0; ni < 4; ++ni)
        acc[mi][ni] = __builtin_amdgcn_mfma_f32_16x16x32_bf16(af[mi], bfr[ni], acc[mi][ni], 0, 0, 0);
  }

  // ---- epilogue: bias (+ReLU) (+column stats), store ----
#pragma unroll
  for (int ni = 0; ni < 4; ++ni) {
    int gn = n0 + wn + ni * 16 + lr;
    bool store_c = (gn < storeN);
    bool ncol = (gn < Nn);
    float bv = ncol ? bias[gn] : 0.f;
    float s = 0.f, q = 0.f;
#pragma unroll
    for (int mi = 0; mi < 4; ++mi) {
      int gmb = m0 + wm + mi * 16 + quad * 4;
#pragma unroll
      for (int r = 0; r < 4; ++r) {
        int gm = gmb + r;
        float v = acc[mi][ni][r] + bv;
        if (RELU) v = fmaxf(v, 0.f);
        if (gm < M && store_c) {
          if constexpr (CF32) ((float*)Cv)[(size_t)gm * ldc + gn] = v;
          else ((unsigned short*)Cv)[(size_t)gm * ldc + gn] = f2b(v);
          if (STATS && ncol) { s += v; q += v * v; }
        }
      }
    }
    if constexpr (STATS) {
      s += __shfl_xor(s, 16); q += __shfl_xor(q, 16);
      s += __shfl_xor(s, 32); q += __shfl_xor(q, 32);
      if (quad == 0 && ncol) {
        unsafeAtomicAdd(&colsum[gn], s);
        unsafeAtomicAdd(&colsumsq[gn], q);
      }
    }
  }
}

// ---------- BatchNorm finalize: scale/shift per column ----------
__global__ void bn_finalize(const float* __restrict__ colsum, const float* __restrict__ colsumsq,
                            const float* __restrict__ gamma, const float* __restrict__ beta,
                            float2* __restrict__ ss, int D, float invN) {
  int d = blockIdx.x * blockDim.x + threadIdx.x;
  if (d >= D) return;
  float mean = colsum[d] * invN;
  float var = fmaxf(colsumsq[d] * invN - mean * mean, 0.f);
  float sc = rsqrtf(var + 1e-5f) * gamma[d];
  float sh = beta[d] - mean * sc;
  ss[d] = make_float2(sc, sh);
}

// ---------- BatchNorm apply (in place, float4 vectorized; requires D%4==0) ----------
__global__ void bn_apply4(float4v* __restrict__ out, const float2* __restrict__ ss,
                          int total4, int cquads) {
  int idx = blockIdx.x * blockDim.x + threadIdx.x;
  if (idx >= total4) return;
  int c = (idx % cquads) * 4;
  float4v v = out[idx];
  float2 p0 = ss[c], p1 = ss[c + 1], p2 = ss[c + 2], p3 = ss[c + 3];
  v[0] = v[0] * p0.x + p0.y;
  v[1] = v[1] * p1.x + p1.y;
  v[2] = v[2] * p2.x + p2.y;
  v[3] = v[3] * p3.x + p3.y;
  out[idx] = v;
}

__global__ void bn_apply1(float* __restrict__ out, const float2* __restrict__ ss,
                          int total, int D) {
  int idx = blockIdx.x * blockDim.x + threadIdx.x;
  if (idx >= total) return;
  float2 p = ss[idx % D];
  out[idx] = out[idx] * p.x + p.y;
}

// ---------- launch ----------
extern "C" void kernel_launch(void* const* d_in, const int* in_sizes, int n_in,
                              void* d_out, int out_size, void* d_ws, size_t ws_size,
                              hipStream_t stream) {
  const float* nf  = (const float*)d_in[0];
  const int*   src = (const int*)d_in[1];
  const int*   dst = (const int*)d_in[2];
  const int*   ef0 = (const int*)d_in[3];
  const int*   ef1 = (const int*)d_in[4];
  const float* ew0 = (const float*)d_in[5];
  const float* eb0 = (const float*)d_in[6];
  const float* ew1 = (const float*)d_in[7];
  const float* eb1 = (const float*)d_in[8];
  const float* w1  = (const float*)d_in[9];
  const float* b1  = (const float*)d_in[10];
  const float* w2  = (const float*)d_in[11];
  const float* b2  = (const float*)d_in[12];
  const float* gam = (const float*)d_in[13];
  const float* bet = (const float*)d_in[14];

  const int D = in_sizes[13];          // 300
  const int N = in_sizes[0] / D;       // 100000
  const int E = in_sizes[1];           // 200000
  const int H = in_sizes[10];          // 600
  const int NUM0 = in_sizes[5] / D;    // 6
  const int NUM1 = in_sizes[7] / D;    // 3
  const int KP1 = (D + 31) / 32 * 32;  // 320
  const int NP1 = (H + 127) / 128 * 128;  // 640
  const int KP2 = (H + 31) / 32 * 32;  // 608
  const int NP2 = (D + 127) / 128 * 128;  // 384 (grid cover; B rows guarded at 320)
  const int BROWS1 = (H + 63) / 64 * 64;  // 640 rows allocated for wT1
  const int BROWS2 = (D + 63) / 64 * 64;  // 320 rows allocated for wT2
  const int nb  = (N + 1023) / 1024;   // scan blocks (<=256)

  char* ws = (char*)d_ws;
  size_t off = 0;
  // ---- zeroed region ----
  float* colsum   = (float*)(ws + off); off += 4096;
  float* colsumsq = (float*)(ws + off); off += 4096;
  short* wT1      = (short*)(ws + off); off += (size_t)BROWS1 * KP1 * 2;
  short* wT2      = (short*)(ws + off); off += (size_t)BROWS2 * KP2 * 2;
  int*   deg      = (int*)(ws + off);   off += (size_t)N * 4;
  int*   tmp      = (int*)(ws + off);   off += (size_t)N * 4;
  size_t zero_bytes = off;
  // ---- uninitialized region ----
  float2* ss      = (float2*)(ws + off); off += 4096;
  float* w01      = (float*)(ws + off);  off += (size_t)NUM0 * NUM1 * D * 4;
  int*   offp     = (int*)(ws + off);    off += (size_t)N * 4;
  int*   bsum     = (int*)(ws + off);    off += 4096;
  int2*  ebp      = (int2*)(ws + off);   off += (size_t)E * 8;
  unsigned short* aggb = (unsigned short*)(ws + off); off += (size_t)N * KP1 * 2;
  short* h1       = (short*)(ws + off);  off += (size_t)N * KP2 * 2;

  hipMemsetAsync(d_ws, 0, zero_bytes, stream);

  {  // w1: (D x H) fp32 -> wT1: (H rows x KP1 cols) bf16
    int tot = D * H;
    transpose_pad<<<(tot + 255) / 256, 256, 0, stream>>>(w1, wT1, D, H, KP1, tot);
  }
  {  // w2: (H x D) fp32 -> wT2: (D rows x KP2 cols) bf16
    int tot = H * D;
    transpose_pad<<<(tot + 255) / 256, 256, 0, stream>>>(w2, wT2, H, D, KP2, tot);
  }
  {  // combined edge-embedding table
    int tot = NUM0 * NUM1 * D;
    build_w01<<<(tot + 255) / 256, 256, 0, stream>>>(ew0, ew1, w01, D, NUM1, tot);
  }
  // ---- CSR build ----
  count_deg<<<(E + 255) / 256, 256, 0, stream>>>(dst, deg, E);
  scan1<<<nb, 256, 0, stream>>>(deg, offp, bsum, N);
  scan2<<<1, 256, 0, stream>>>(bsum, nb);
  fill_csr<<<(E + 255) / 256, 256, 0, stream>>>(dst, src, ef0, ef1, offp, bsum, tmp,
                                                ebp, NUM1, E);
  // ---- gather (atomic-free aggregation, bf16 out) ----
  {
    int total = N * (KP1 / 4);
    gather_agg<<<(total + 255) / 256, 256, 0, stream>>>(
        nf, w01, eb0, eb1, deg, offp, bsum, ebp, aggb, D, KP1, total);
  }
  const int nrowb = (N + 127) / 128;
  {  // h1 = relu(aggb @ w1 + b1), bf16, stride KP2; true zeros in cols [H, KP2)
    int ncolb = NP1 / 128;             // 5
    gemm_bias<true, false, false><<<nrowb * ncolb, 256, 0, stream>>>(
        (const short*)aggb, KP1, wT1, KP1, BROWS1, b1,
        h1, KP2, KP2, N, H, KP1, ncolb, nullptr, nullptr);
  }
  {  // h = h1 @ w2 + b2 (+ column stats), fp32 out
    int ncolb = NP2 / 128;             // 3
    gemm_bias<false, true, true><<<nrowb * ncolb, 256, 0, stream>>>(
        h1, KP2, wT2, KP2, BROWS2, b2,
        d_out, D, D, N, D, KP2, ncolb, colsum, colsumsq);
  }
  bn_finalize<<<(D + 255) / 256, 256, 0, stream>>>(colsum, colsumsq, gam, bet, ss, D,
                                                   1.0f / (float)N);
  if ((D & 3) == 0) {
    int total4 = N * (D / 4);
    bn_apply4<<<(total4 + 255) / 256, 256, 0, stream>>>((float4v*)d_out, ss, total4, D / 4);
  } else {
    int tot = N * D;
    bn_apply1<<<(tot + 255) / 256, 256, 0, stream>>>((float*)d_out, ss, tot, D);
  }
}

// Round 3
// 583.219 us; speedup vs baseline: 1.2615x; 1.1967x over previous
//
#include <hip/hip_runtime.h>
#include <stdint.h>

// Shapes assumed (fixed by the problem): D=300 (KP1=320), H=600 (KP2=608), D%4==0.

// ---------- helpers ----------
typedef __attribute__((ext_vector_type(8))) short short8;
typedef __attribute__((ext_vector_type(4))) short short4v;
typedef __attribute__((ext_vector_type(4))) float float4v;

__device__ inline unsigned short f2b(float f) {
  union { float f; unsigned int i; } v; v.f = f;
  unsigned int i = v.i;
  i += 0x7fffu + ((i >> 16) & 1u);   // round-to-nearest-even
  return (unsigned short)(i >> 16);
}

// async global->LDS, 16B per lane; LDS dest is wave-uniform base + lane*16
__device__ __forceinline__ void gl_lds16(const short* g, short* l) {
  __builtin_amdgcn_global_load_lds(
      (const __attribute__((address_space(1))) unsigned int*)g,
      (__attribute__((address_space(3))) unsigned int*)l,
      16, 0, 0);
}

// ---------- transpose fp32 -> bf16, zero-padded output (pad pre-zeroed by memset) ----------
__global__ void transpose_pad(const float* __restrict__ in, short* __restrict__ out,
                              int R, int C, int outStride, int total) {
  int idx = blockIdx.x * blockDim.x + threadIdx.x;
  if (idx >= total) return;
  int r = idx / C, c = idx - r * C;
  out[(size_t)c * outStride + r] = (short)f2b(in[idx]);
}

// ---------- combined edge-embedding table: w01[f0*NUM1+f1][d] = w0[f0][d]+w1[f1][d] ----------
__global__ void build_w01(const float* __restrict__ w0, const float* __restrict__ w1,
                          float* __restrict__ w01, int D, int NUM1, int total) {
  int i = blockIdx.x * blockDim.x + threadIdx.x;
  if (i >= total) return;
  int f01 = i / D, d = i - f01 * D;
  int f0 = f01 / NUM1, f1 = f01 - f0 * NUM1;
  w01[i] = w0[f0 * D + d] + w1[f1 * D + d];
}

// ---------- CSR build: count, scan, fill ----------
__global__ void count_deg(const int* __restrict__ dst, int* __restrict__ deg, int E) {
  int e = blockIdx.x * blockDim.x + threadIdx.x;
  if (e < E) atomicAdd(&deg[dst[e]], 1);
}

__global__ void scan1(const int* __restrict__ deg, int* __restrict__ offp,
                      int* __restrict__ bsum, int n) {
  __shared__ int sh[256];
  const int t = threadIdx.x;
  const int base = blockIdx.x * 1024 + t * 4;
  int v[4], s = 0;
#pragma unroll
  for (int j = 0; j < 4; ++j) { int i = base + j; v[j] = (i < n) ? deg[i] : 0; s += v[j]; }
  sh[t] = s;
  __syncthreads();
  for (int d = 1; d < 256; d <<= 1) {
    int x = (t >= d) ? sh[t - d] : 0;
    __syncthreads();
    sh[t] += x;
    __syncthreads();
  }
  int excl = (t > 0) ? sh[t - 1] : 0;
  if (t == 255) bsum[blockIdx.x] = sh[255];
#pragma unroll
  for (int j = 0; j < 4; ++j) { int i = base + j; if (i < n) offp[i] = excl; excl += v[j]; }
}

__global__ void scan2(int* __restrict__ bsum, int nb) {
  __shared__ int sh[256];
  const int t = threadIdx.x;
  sh[t] = (t < nb) ? bsum[t] : 0;
  __syncthreads();
  for (int d = 1; d < 256; d <<= 1) {
    int x = (t >= d) ? sh[t - d] : 0;
    __syncthreads();
    sh[t] += x;
    __syncthreads();
  }
  if (t < nb) bsum[t] = (t > 0) ? sh[t - 1] : 0;
}

// fill CSR with pre-gathered per-edge payload: {src, f0*NUM1+f1}
__global__ void fill_csr(const int* __restrict__ dst, const int* __restrict__ src,
                         const int* __restrict__ ef0, const int* __restrict__ ef1,
                         const int* __restrict__ offp, const int* __restrict__ bsum,
                         int* __restrict__ tmp, int2* __restrict__ ebp, int NUM1, int E) {
  int e = blockIdx.x * blockDim.x + threadIdx.x;
  if (e >= E) return;
  int dn = dst[e];
  int pos = offp[dn] + bsum[dn >> 10] + atomicAdd(&tmp[dn], 1);
  ebp[pos] = make_int2(src[e], ef0[e] * NUM1 + ef1[e]);
}

// ---------- gather: aggb[node] = sum_e (nf[src]+w01[f01]) + deg*(b0+b1), bf16 out ----------
__global__ void gather_agg(const float* __restrict__ nf, const float* __restrict__ w01,
                           const float* __restrict__ b0f, const float* __restrict__ b1f,
                           const int* __restrict__ deg, const int* __restrict__ offp,
                           const int* __restrict__ bsum, const int2* __restrict__ ebp,
                           unsigned short* __restrict__ aggb,
                           int D, int ldab, int total) {
  int idx = blockIdx.x * blockDim.x + threadIdx.x;
  if (idx >= total) return;
  const int quads = ldab >> 2;
  int node = idx / quads;
  int q = idx - node * quads;
  int d = q * 4;
  unsigned short* op = &aggb[(size_t)node * ldab + d];
  if (d >= D) {  // zero the pad columns so GEMM1's A pad is clean
    short4v z = {0, 0, 0, 0};
    *(short4v*)op = z;
    return;
  }
  int dg = deg[node];
  int o = offp[node] + bsum[node >> 10];
  float4v acc = {0.f, 0.f, 0.f, 0.f};
  for (int j = 0; j < dg; ++j) {
    int2 p = ebp[o + j];
    float4v nv = *(const float4v*)&nf[(size_t)p.x * D + d];
    float4v wv = *(const float4v*)&w01[(size_t)p.y * D + d];
    acc += nv + wv;
  }
  float4v bb = *(const float4v*)&b0f[d];
  float4v b2v = *(const float4v*)&b1f[d];
  acc += (float)dg * (bb + b2v);
  short4v r;
#pragma unroll
  for (int j = 0; j < 4; ++j) r[j] = (short)f2b(acc[j]);
  *(short4v*)op = r;
}

// ---------- MFMA GEMM: global_load_lds staging, XOR-swizzled linear LDS, XCD-swizzled ----------
// A bf16 [MP][lda], MP a multiple of 128 (pad rows may be garbage: row-isolated, never stored).
// BT [BrowsAlloc][ldbt] bf16; grid cols * 64 must be <= BT row allocation.
// Source-side swizzle: LDS[row][u] holds A[row][u ^ sw(row)], sw(r)=(r^(r>>2))&3 (16B units);
// fragment reads apply the same XOR -> 2-way bank conflicts (free).
template<bool RELU, bool STATS, bool CF32>
__global__ __launch_bounds__(256, 6)
void gemm_lds(const short* __restrict__ A, int lda,
              const short* __restrict__ BT, int ldbt,
              const float* __restrict__ bias,
              void* __restrict__ Cv, int ldc, int storeN,
              int M, int Nn, int KP, int ncolb,
              float* __restrict__ colsum, float* __restrict__ colsumsq) {
  constexpr int BM = 128, BN = 64, BK = 32;
  __shared__ __align__(16) short Al[BM * BK];   // 8 KB, linear [row][32]
  __shared__ __align__(16) short Bl[BN * BK];   // 4 KB

  // ---- bijective XCD chunk swizzle; w = by*ncolb + bx (col fastest -> A panel shares XCD L2)
  const int nwg = gridDim.x;
  const int b = blockIdx.x;
  const int qq = nwg >> 3, rr = nwg & 7;
  const int xcd = b & 7, ii = b >> 3;
  const int w = ((xcd < rr) ? xcd * (qq + 1) : rr * (qq + 1) + (xcd - rr) * qq) + ii;
  const int by = w / ncolb, bx = w - by * ncolb;
  const int m0 = by * BM, n0 = bx * BN;

  const int t = threadIdx.x;
  const int wave = t >> 6, lane = t & 63, quad = lane >> 4, lr = lane & 15;
  const int wm = (wave >> 1) * 64, wn = (wave & 1) * 32;

  // ---- staging sources (k-invariant): dest byte = roundbase + lane*16 ----
  const int au = lane & 3;
  const int arow0 = (wave * 2 + 0) * 16 + (lane >> 2);
  const int arow1 = (wave * 2 + 1) * 16 + (lane >> 2);
  const int asw0 = au ^ ((arow0 ^ (arow0 >> 2)) & 3);
  const int asw1 = au ^ ((arow1 ^ (arow1 >> 2)) & 3);
  const short* asrc0 = A + (size_t)(m0 + arow0) * lda + asw0 * 8;
  const short* asrc1 = A + (size_t)(m0 + arow1) * lda + asw1 * 8;
  short* adst0 = &Al[(wave * 2 + 0) * 512];
  short* adst1 = &Al[(wave * 2 + 1) * 512];
  const int brow = wave * 16 + (lane >> 2);
  const int bsw = au ^ ((brow ^ (brow >> 2)) & 3);
  const short* bsrc = BT + (size_t)(n0 + brow) * ldbt + bsw * 8;
  short* bdst = &Bl[wave * 512];

  // ---- fragment read offsets (k-invariant, same XOR) ----
  int aoff[4], boff[2];
#pragma unroll
  for (int mi = 0; mi < 4; ++mi) {
    int r = wm + mi * 16 + lr;
    aoff[mi] = r * BK + (quad ^ ((r ^ (r >> 2)) & 3)) * 8;
  }
#pragma unroll
  for (int ni = 0; ni < 2; ++ni) {
    int r = wn + ni * 16 + lr;
    boff[ni] = r * BK + (quad ^ ((r ^ (r >> 2)) & 3)) * 8;
  }

  const float4v fzero = {0.f, 0.f, 0.f, 0.f};
  float4v acc[4][2];
#pragma unroll
  for (int mi = 0; mi < 4; ++mi) {
    acc[mi][0] = fzero; acc[mi][1] = fzero;
  }

  for (int k0 = 0; k0 < KP; k0 += BK) {
    __syncthreads();           // previous iteration's LDS reads complete
    gl_lds16(asrc0 + k0, adst0);
    gl_lds16(asrc1 + k0, adst1);
    gl_lds16(bsrc + k0, bdst);
    __syncthreads();           // drains vmcnt -> staged data visible
    short8 af[4], bfr[2];
#pragma unroll
    for (int mi = 0; mi < 4; ++mi) af[mi] = *(const short8*)&Al[aoff[mi]];
#pragma unroll
    for (int ni = 0; ni < 2; ++ni) bfr[ni] = *(const short8*)&Bl[boff[ni]];
#pragma unroll
    for (int mi = 0; mi < 4; ++mi) {
      acc[mi][0] = __builtin_amdgcn_mfma_f32_16x16x32_bf16(af[mi], bfr[0], acc[mi][0], 0, 0, 0);
      acc[mi][1] = __builtin_amdgcn_mfma_f32_16x16x32_bf16(af[mi], bfr[1], acc[mi][1], 0, 0, 0);
    }
  }

  // ---- epilogue: bias (+ReLU) (+column stats), store ----
#pragma unroll
  for (int ni = 0; ni < 2; ++ni) {
    int gn = n0 + wn + ni * 16 + lr;
    bool store_c = (gn < storeN);
    bool ncol = (gn < Nn);
    float bv = ncol ? bias[gn] : 0.f;
    float s = 0.f, q = 0.f;
#pragma unroll
    for (int mi = 0; mi < 4; ++mi) {
      int gmb = m0 + wm + mi * 16 + quad * 4;
#pragma unroll
      for (int r = 0; r < 4; ++r) {
        int gm = gmb + r;
        float v = acc[mi][ni][r] + bv;
        if (RELU) v = fmaxf(v, 0.f);
        if (gm < M && store_c) {
          if constexpr (CF32) ((float*)Cv)[(size_t)gm * ldc + gn] = v;
          else ((unsigned short*)Cv)[(size_t)gm * ldc + gn] = f2b(v);
          if (STATS && ncol) { s += v; q += v * v; }
        }
      }
    }
    if constexpr (STATS) {
      s += __shfl_xor(s, 16); q += __shfl_xor(q, 16);
      s += __shfl_xor(s, 32); q += __shfl_xor(q, 32);
      if (quad == 0 && ncol) {
        unsafeAtomicAdd(&colsum[gn], s);
        unsafeAtomicAdd(&colsumsq[gn], q);
      }
    }
  }
}

// ---------- BatchNorm finalize: scale/shift per column ----------
__global__ void bn_finalize(const float* __restrict__ colsum, const float* __restrict__ colsumsq,
                            const float* __restrict__ gamma, const float* __restrict__ beta,
                            float2* __restrict__ ss, int D, float invN) {
  int d = blockIdx.x * blockDim.x + threadIdx.x;
  if (d >= D) return;
  float mean = colsum[d] * invN;
  float var = fmaxf(colsumsq[d] * invN - mean * mean, 0.f);
  float sc = rsqrtf(var + 1e-5f) * gamma[d];
  float sh = beta[d] - mean * sc;
  ss[d] = make_float2(sc, sh);
}

// ---------- BatchNorm apply (in place, float4 vectorized; requires D%4==0) ----------
__global__ void bn_apply4(float4v* __restrict__ out, const float2* __restrict__ ss,
                          int total4, int cquads) {
  int idx = blockIdx.x * blockDim.x + threadIdx.x;
  if (idx >= total4) return;
  int c = (idx % cquads) * 4;
  float4v v = out[idx];
  float2 p0 = ss[c], p1 = ss[c + 1], p2 = ss[c + 2], p3 = ss[c + 3];
  v[0] = v[0] * p0.x + p0.y;
  v[1] = v[1] * p1.x + p1.y;
  v[2] = v[2] * p2.x + p2.y;
  v[3] = v[3] * p3.x + p3.y;
  out[idx] = v;
}

__global__ void bn_apply1(float* __restrict__ out, const float2* __restrict__ ss,
                          int total, int D) {
  int idx = blockIdx.x * blockDim.x + threadIdx.x;
  if (idx >= total) return;
  float2 p = ss[idx % D];
  out[idx] = out[idx] * p.x + p.y;
}

// ---------- launch ----------
extern "C" void kernel_launch(void* const* d_in, const int* in_sizes, int n_in,
                              void* d_out, int out_size, void* d_ws, size_t ws_size,
                              hipStream_t stream) {
  const float* nf  = (const float*)d_in[0];
  const int*   src = (const int*)d_in[1];
  const int*   dst = (const int*)d_in[2];
  const int*   ef0 = (const int*)d_in[3];
  const int*   ef1 = (const int*)d_in[4];
  const float* ew0 = (const float*)d_in[5];
  const float* eb0 = (const float*)d_in[6];
  const float* ew1 = (const float*)d_in[7];
  const float* eb1 = (const float*)d_in[8];
  const float* w1  = (const float*)d_in[9];
  const float* b1  = (const float*)d_in[10];
  const float* w2  = (const float*)d_in[11];
  const float* b2  = (const float*)d_in[12];
  const float* gam = (const float*)d_in[13];
  const float* bet = (const float*)d_in[14];

  const int D = in_sizes[13];          // 300
  const int N = in_sizes[0] / D;       // 100000
  const int E = in_sizes[1];           // 200000
  const int H = in_sizes[10];          // 600
  const int NUM0 = in_sizes[5] / D;    // 6
  const int NUM1 = in_sizes[7] / D;    // 3
  const int KP1 = (D + 31) / 32 * 32;  // 320
  const int KP2 = (H + 31) / 32 * 32;  // 608
  const int NCB1 = (H + 63) / 64;      // 10 col blocks, covers 640
  const int NCB2 = (D + 63) / 64;      // 5 col blocks, covers 320
  const int BROWS1 = NCB1 * 64;        // 640 rows allocated for wT1
  const int BROWS2 = NCB2 * 64;        // 320 rows allocated for wT2
  const int nrowb = (N + 127) / 128;   // 782
  const int MP = nrowb * 128;          // 100096 padded A rows
  const int nb  = (N + 1023) / 1024;   // scan blocks (<=256)

  char* ws = (char*)d_ws;
  size_t off = 0;
  // ---- zeroed region ----
  float* colsum   = (float*)(ws + off); off += 4096;
  float* colsumsq = (float*)(ws + off); off += 4096;
  short* wT1      = (short*)(ws + off); off += (size_t)BROWS1 * KP1 * 2;
  short* wT2      = (short*)(ws + off); off += (size_t)BROWS2 * KP2 * 2;
  int*   deg      = (int*)(ws + off);   off += (size_t)N * 4;
  int*   tmp      = (int*)(ws + off);   off += (size_t)N * 4;
  size_t zero_bytes = off;
  // ---- uninitialized region ----
  float2* ss      = (float2*)(ws + off); off += 4096;
  float* w01      = (float*)(ws + off);  off += (size_t)NUM0 * NUM1 * D * 4;
  int*   offp     = (int*)(ws + off);    off += (size_t)N * 4;
  int*   bsum     = (int*)(ws + off);    off += 4096;
  int2*  ebp      = (int2*)(ws + off);   off += (size_t)E * 8;
  unsigned short* aggb = (unsigned short*)(ws + off); off += (size_t)MP * KP1 * 2;
  short* h1       = (short*)(ws + off);  off += (size_t)MP * KP2 * 2;

  hipMemsetAsync(d_ws, 0, zero_bytes, stream);

  {  // w1: (D x H) fp32 -> wT1: (H rows x KP1 cols) bf16
    int tot = D * H;
    transpose_pad<<<(tot + 255) / 256, 256, 0, stream>>>(w1, wT1, D, H, KP1, tot);
  }
  {  // w2: (H x D) fp32 -> wT2: (D rows x KP2 cols) bf16
    int tot = H * D;
    transpose_pad<<<(tot + 255) / 256, 256, 0, stream>>>(w2, wT2, H, D, KP2, tot);
  }
  {  // combined edge-embedding table
    int tot = NUM0 * NUM1 * D;
    build_w01<<<(tot + 255) / 256, 256, 0, stream>>>(ew0, ew1, w01, D, NUM1, tot);
  }
  // ---- CSR build ----
  count_deg<<<(E + 255) / 256, 256, 0, stream>>>(dst, deg, E);
  scan1<<<nb, 256, 0, stream>>>(deg, offp, bsum, N);
  scan2<<<1, 256, 0, stream>>>(bsum, nb);
  fill_csr<<<(E + 255) / 256, 256, 0, stream>>>(dst, src, ef0, ef1, offp, bsum, tmp,
                                                ebp, NUM1, E);
  // ---- gather (atomic-free aggregation, bf16 out) ----
  {
    int total = N * (KP1 / 4);
    gather_agg<<<(total + 255) / 256, 256, 0, stream>>>(
        nf, w01, eb0, eb1, deg, offp, bsum, ebp, aggb, D, KP1, total);
  }
  {  // h1 = relu(aggb @ w1 + b1), bf16, stride KP2; true zeros in cols [H, KP2)
    gemm_lds<true, false, false><<<nrowb * NCB1, 256, 0, stream>>>(
        (const short*)aggb, KP1, wT1, KP1, b1,
        h1, KP2, KP2, N, H, KP1, NCB1, nullptr, nullptr);
  }
  {  // h = h1 @ w2 + b2 (+ column stats), fp32 out
    gemm_lds<false, true, true><<<nrowb * NCB2, 256, 0, stream>>>(
        h1, KP2, wT2, KP2, b2,
        d_out, D, D, N, D, KP2, NCB2, colsum, colsumsq);
  }
  bn_finalize<<<(D + 255) / 256, 256, 0, stream>>>(colsum, colsumsq, gam, bet, ss, D,
                                                   1.0f / (float)N);
  if ((D & 3) == 0) {
    int total4 = N * (D / 4);
    bn_apply4<<<(total4 + 255) / 256, 256, 0, stream>>>((float4v*)d_out, ss, total4, D / 4);
  } else {
    int tot = N * D;
    bn_apply1<<<(tot + 255) / 256, 256, 0, stream>>>((float*)d_out, ss, tot, D);
  }
}